// Round 1
// 281.550 us; speedup vs baseline: 1.0131x; 1.0131x over previous
//
#include <hip/hip_runtime.h>
#include <math.h>

#define BB 4
#define SS 8192
#define HH 16
#define DD 64
#define ROT 32
#define NG (BB * SS * HH)  // 524288 token-head rows
#define RPB 128            // rows per block
#define LSTR 65            // LDS row stride in floats (pad +1 -> rotated banks)
#define TPB 512            // threads per block (8 waves) -> 4 blocks/CU = 32 waves/CU

// ---------------------------------------------------------------------------
// Merged setup: G_comb = I @ G_0 @ ... @ G_31 built in LDS (threads 0..63,
// column-op per row, no syncs needed among them), then M = G @ matrix.
// Each of the 16 blocks redundantly builds G (trivial: 64x32 ops) and
// computes its 256-element slice of M. Saves one kernel launch.
// i==j edge: .at chain leaves G[i,i]=sin -> column i scaled by sin.
// ---------------------------------------------------------------------------
__global__ void setup_GM(const float* __restrict__ thetas,
                         const float* __restrict__ tscale,
                         const int* __restrict__ pairs,
                         const float* __restrict__ matrix,
                         float* __restrict__ M) {
  __shared__ float Gs[DD][DD];
  const int t = threadIdx.x;
  if (t < DD) {
    for (int c = 0; c < DD; ++c) Gs[t][c] = (t == c) ? 1.0f : 0.0f;
    const float ts = tscale[0];
    for (int r = 0; r < ROT; ++r) {
      const int i = pairs[2 * r], j = pairs[2 * r + 1];
      const float th = thetas[r] * ts;
      const float cc = cosf(th), sn = sinf(th);
      if (i == j) {
        Gs[t][i] *= sn;
      } else {
        const float a = Gs[t][i], b = Gs[t][j];
        Gs[t][i] = a * cc + b * sn;
        Gs[t][j] = b * cc - a * sn;
      }
    }
  }
  __syncthreads();
  const int e = blockIdx.x * 256 + t;
  const int row = e >> 6, col = e & 63;  // row wave-uniform -> LDS broadcast
  float a0 = 0.f, a1 = 0.f, a2 = 0.f, a3 = 0.f;
  for (int k = 0; k < DD; k += 4) {
    a0 = fmaf(Gs[row][k], matrix[k * DD + col], a0);
    a1 = fmaf(Gs[row][k + 1], matrix[(k + 1) * DD + col], a1);
    a2 = fmaf(Gs[row][k + 2], matrix[(k + 2) * DD + col], a2);
    a3 = fmaf(Gs[row][k + 3], matrix[(k + 3) * DD + col], a3);
  }
  M[e] = (a0 + a1) + (a2 + a3);
}

// cos/sin table PRESCALED by 32 (the sqrt(dims) factor fused here).
// tab[s*64 + d] = 32*cos(s*invf[d]); tab[s*64 + 32 + d] = 32*sin(...)
__global__ void setup_table(const float* __restrict__ invf,
                            float* __restrict__ tab) {
  const int idx = blockIdx.x * 256 + threadIdx.x;
  if (idx >= SS * 32) return;
  const int s = idx >> 5, d = idx & 31;
  const float ang = (float)s * invf[d];
  tab[s * 64 + d] = 32.0f * cosf(ang);
  tab[s * 64 + 32 + d] = 32.0f * sinf(ang);
}

// ---------------------------------------------------------------------------
// Main kernel: coalesced load -> LDS -> per-thread 16-col matvec (M scalar-
// loaded, wave-uniform) -> RoPE epilogue -> LDS -> coalesced store.
// 512 threads/block over the same 128-row tile: thread (r,h) h=0..3 computes
// cols [16h,16h+16). Same per-element accumulation order as the 256-thread
// version -> bitwise-identical output.
// ---------------------------------------------------------------------------
__global__ __launch_bounds__(TPB, 8) void apply_rot(
    const float* __restrict__ x, const float* __restrict__ M,
    const float* __restrict__ tab, const float* __restrict__ invf,
    float* __restrict__ out) {
  __shared__ float lds[RPB * LSTR];  // 33280 B -> 4 blocks/CU (8 waves each)
  const int tid = threadIdx.x;
  const size_t R0 = (size_t)blockIdx.x * RPB;

  // Phase 1: coalesced float4 loads of 128 rows -> padded LDS tile.
  const float4* __restrict__ xg = (const float4*)x + R0 * 16;
#pragma unroll
  for (int i = 0; i < 4; ++i) {
    const int f = i * TPB + tid;  // float4 index in tile [0,2048)
    const int row = f >> 4, c4 = f & 15;
    const float4 v = xg[f];
    *(float4*)&lds[row * LSTR + c4 * 4] = v;
  }
  __syncthreads();

  // Phase 2: thread (r,h) computes cols [16h, 16h+16) of row r.
  const int r = tid & (RPB - 1);
  const int h = __builtin_amdgcn_readfirstlane(tid >> 7);  // 0..3, wave-uniform
  const float* __restrict__ Mh = M + h * 16;
  const float* __restrict__ xr = &lds[r * LSTR];

  float acc[16];
#pragma unroll
  for (int c = 0; c < 16; ++c) acc[c] = 0.0f;

#pragma unroll 4
  for (int k4 = 0; k4 < 16; ++k4) {
    const float4 xv = *(const float4*)&xr[k4 * 4];
    const float* __restrict__ m0 = Mh + k4 * 4 * DD;  // uniform -> s_load
#pragma unroll
    for (int c = 0; c < 16; ++c) acc[c] = fmaf(xv.x, m0[c], acc[c]);
#pragma unroll
    for (int c = 0; c < 16; ++c) acc[c] = fmaf(xv.y, m0[DD + c], acc[c]);
#pragma unroll
    for (int c = 0; c < 16; ++c) acc[c] = fmaf(xv.z, m0[2 * DD + c], acc[c]);
#pragma unroll
    for (int c = 0; c < 16; ++c) acc[c] = fmaf(xv.w, m0[3 * DD + c], acc[c]);
  }

  // Epilogue: RoPE pairs (2d,2d+1) -> out cols d (lo) and 32+d (hi), d=8h+d'.
  const int g = (int)R0 + r;
  const int spos = (g >> 4) & (SS - 1);
  float cz[8], sz[8];
  if (tab) {
    const float4* __restrict__ tc = (const float4*)(tab + spos * 64 + h * 8);
    const float4* __restrict__ tn =
        (const float4*)(tab + spos * 64 + 32 + h * 8);
#pragma unroll
    for (int q = 0; q < 2; ++q) {
      *(float4*)&cz[4 * q] = tc[q];
      *(float4*)&sz[4 * q] = tn[q];
    }
  } else {
#pragma unroll
    for (int d = 0; d < 8; ++d) {
      const float ang = (float)spos * invf[h * 8 + d];
      cz[d] = 32.0f * cosf(ang);
      sz[d] = 32.0f * sinf(ang);
    }
  }

  __syncthreads();  // all LDS x-reads complete before overwrite
  float* __restrict__ orow = &lds[r * LSTR];
#pragma unroll
  for (int q = 0; q < 2; ++q) {
    float4 lo, hi;
#pragma unroll
    for (int d = 0; d < 4; ++d) {
      const int dd = 4 * q + d;
      const float e = acc[2 * dd], o = acc[2 * dd + 1];
      ((float*)&lo)[d] = e * cz[dd] - o * sz[dd];
      ((float*)&hi)[d] = e * sz[dd] + o * cz[dd];
    }
    *(float4*)&orow[8 * h + 4 * q] = lo;
    *(float4*)&orow[32 + 8 * h + 4 * q] = hi;
  }
  __syncthreads();

  // Phase 3: coalesced float4 stores from LDS.
  float4* __restrict__ og = (float4*)out + R0 * 16;
#pragma unroll
  for (int i = 0; i < 4; ++i) {
    const int f = i * TPB + tid;
    og[f] = *(float4*)&lds[(f >> 4) * LSTR + (f & 15) * 4];
  }
}

// ---------------------------------------------------------------------------
extern "C" void kernel_launch(void* const* d_in, const int* in_sizes, int n_in,
                              void* d_out, int out_size, void* d_ws,
                              size_t ws_size, hipStream_t stream) {
  const float* x = (const float*)d_in[0];       // (4, 8192, 1024) f32
  const float* matrix = (const float*)d_in[1];  // (64, 64) f32
  const float* thetas = (const float*)d_in[2];  // (32,) f32
  const float* tscale = (const float*)d_in[3];  // (1,) f32
  const float* invf = (const float*)d_in[4];    // (32,) f32
  const int* pairs = (const int*)d_in[5];       // (32, 2) i32
  float* out = (float*)d_out;

  float* M = (float*)d_ws;   // 4096 f
  float* tab = M + DD * DD;  // SS*64 f = 2 MB
  const size_t need = (size_t)(DD * DD + SS * 64) * sizeof(float);
  const bool have_tab = ws_size >= need;

  setup_GM<<<16, 256, 0, stream>>>(thetas, tscale, pairs, matrix, M);
  if (have_tab) setup_table<<<(SS * 32) / 256, 256, 0, stream>>>(invf, tab);
  apply_rot<<<NG / RPB, TPB, 0, stream>>>(x, M, have_tab ? tab : nullptr, invf,
                                          out);
}